// Round 7
// baseline (141.369 us; speedup 1.0000x reference)
//
#include <hip/hip_runtime.h>
#include <math.h>

#define T_STEPS 730
#define NB      1000
#define LENF    15
#define NEARZ   1e-5f
#define SGW2    8064           // state width: 8000 gids + 64 pad (junk from tail block)
#define TT      50             // finalize: t-rows per block
#define BBLK    32             // finalize: basins per block

// ===========================================================================
// R7 = R3 (best measured, 113.6us) + ONE change: the scan runs TWO
// independent chains per lane (C=2), statically interleaved.
// R6 post-mortem: byte-halving regressed -> kernels are in-order-issue /
// latency bound, not BW bound.  R3 scan ~131cy/step vs ~40cy chain + ~38cy
// issue: a lone in-order wave serializes chain stalls with issue.  Chain 1
// fills chain 0's stalls (R1's version of this was confounded by scatter
// stores; R3's [t][lane] layout removed that).
//  * block = 64 lanes x 2 chains = 16 basins; x staged in 94KB LDS.
//  * exp2(pet*nbl) is forcing-only -> precomputed in prefetch ((pcp,e)
//    pairs), off the serial step region.
//  * plane stride 8064: last block's 8 invalid basins (chain1) store to
//    padding gids 8000..8063 -> no predicates in the loop.
// ===========================================================================
#define STEP2(V0, V1)                                                          \
  {                                                                            \
    float W0  = (V0).x + S0;                                                   \
    float t0  = fmaf(W0, inv2a0, pb2a0);                                       \
    float d0  = fmaf(t0, t0, -(W0 * boa0));                                    \
    float r0  = __builtin_amdgcn_sqrtf(fmaxf(d0, NEARZ));                      \
    float Y0  = t0 - r0;                                                       \
    float Sn0 = Y0 * (V0).y;                                                   \
    float av0 = W0 - Y0;                                                       \
    float Gn0 = fmaf(pc0, av0, G0) * i1d0;                                     \
    float W1  = (V1).x + S1;                                                   \
    float t1  = fmaf(W1, inv2a1, pb2a1);                                       \
    float d1  = fmaf(t1, t1, -(W1 * boa1));                                    \
    float r1  = __builtin_amdgcn_sqrtf(fmaxf(d1, NEARZ));                      \
    float Y1  = t1 - r1;                                                       \
    float Sn1 = Y1 * (V1).y;                                                   \
    float av1 = W1 - Y1;                                                       \
    float Gn1 = fmaf(pc1, av1, G1) * i1d1;                                     \
    S0 = Sn0; G0 = Gn0; S1 = Sn1; G1 = Gn1;                                    \
    ps0[0]  = make_float2(Sn0, Gn0);                                           \
    ps0[64] = make_float2(Sn1, Gn1);                                           \
    ps0 += SGW2;                                                               \
  }

// LDS prefetch + exp2 precompute: rows up to 735 valid (dups of 729).
#define PREFETCH(B0, B1, CI)                                                   \
  _Pragma("unroll")                                                            \
  for (int j = 0; j < 8; ++j) {                                                \
      float2 v0 = xs[((CI) * 8 + j) * 16 + bl0];                               \
      float2 v1 = xs[((CI) * 8 + j) * 16 + bl1];                               \
      B0[j] = make_float2(v0.x, __builtin_amdgcn_exp2f(v0.y * nbl0));          \
      B1[j] = make_float2(v1.x, __builtin_amdgcn_exp2f(v1.y * nbl1));          \
  }                                                                            \
  __builtin_amdgcn_sched_barrier(0);

__global__ __launch_bounds__(64, 1) void scan_state(const float* __restrict__ x,
                                                    const float* __restrict__ raw,
                                                    float2* __restrict__ sg) {
    __shared__ float4 xs4[5888];               // 736 rows x 16 basins x 8B = 94.2KB
    const float2* xs = (const float2*)xs4;

    const int L   = threadIdx.x;
    const int blk = blockIdx.x;                // 0..62
    const int bl0 = L >> 3;                    // chain0 basin-local 0..7
    const int bl1 = bl0 + 8;                   // chain1 basin-local 8..15
    const int m   = L & 7;
    int b0 = blk * 16 + bl0; if (b0 > NB - 1) b0 = NB - 1;   // clamp (loads only)
    int b1 = blk * 16 + 8 + bl0; if (b1 > NB - 1) b1 = NB - 1;

    // ---- one-time cooperative x -> LDS stage: 4 rounds x 23 float4 -------
    for (int rd = 0; rd < 4; ++rd) {
        float4 tmp[23];
#pragma unroll
        for (int ch = 0; ch < 23; ++ch) {
            int idx = (rd * 23 + ch) * 64 + L; // 0..5887
            int row = idx >> 3;                // t row 0..735
            int col = idx & 7;                 // float4 within row (2 basins)
            row = row < T_STEPS ? row : (T_STEPS - 1);
            int bo = blk * 128 + col * 16;     // byte offset within row
            bo = bo <= 8000 - 16 ? bo : 8000 - 16;   // last-block OOB guard
            tmp[ch] = *(const float4*)((const char*)x + (size_t)row * (NB * 8) + bo);
        }
#pragma unroll
        for (int ch = 0; ch < 23; ++ch) xs4[(rd * 23 + ch) * 64 + L] = tmp[ch];
    }
    __syncthreads();

    // raw layout (B,34) = [a(8), b(8), c(8), d(8), ra, rb]
    const float* rp0 = raw + b0 * 34;
    const float* rp1 = raw + b1 * 34;
    float pa0 = rp0[0 * 8 + m] * 0.9f + 0.1f;
    float pb0 = rp0[1 * 8 + m] * 450.0f + 50.0f;
    float pc0 = rp0[2 * 8 + m];
    float pd0 = rp0[3 * 8 + m] * 0.89f + 0.01f;
    float pa1 = rp1[0 * 8 + m] * 0.9f + 0.1f;
    float pb1 = rp1[1 * 8 + m] * 450.0f + 50.0f;
    float pc1 = rp1[2 * 8 + m];
    float pd1 = rp1[3 * 8 + m] * 0.89f + 0.01f;

    float inv2a0 = 1.0f / (2.0f * pa0);
    float pb2a0  = pb0 * inv2a0;
    float boa0   = pb0 / pa0;
    float nbl0   = -1.4426950408889634f / pb0;  // exp(-pet/b)=exp2(pet*this)
    float i1d0   = 1.0f / (1.0f + pd0);
    float inv2a1 = 1.0f / (2.0f * pa1);
    float pb2a1  = pb1 * inv2a1;
    float boa1   = pb1 / pa1;
    float nbl1   = -1.4426950408889634f / pb1;
    float i1d1   = 1.0f / (1.0f + pd1);

    float S0 = 50.0f, G0 = 10.0f, S1 = 50.0f, G1 = 10.0f;
    float2* ps0 = sg + blk * 128 + L;          // chain1 = ps0[64]; advance SGW2/step

    float2 A0[8], A1[8], B0[8], B1[8], C0[8], C1[8];
    PREFETCH(A0, A1, 0)
    PREFETCH(B0, B1, 1)

    // 15 groups x 48 steps (6 chunks of 8) = 720 steps, + 10-step tail.
    for (int g = 0; g < 15; ++g) {
        const int c0 = 6 * g;
        PREFETCH(C0, C1, c0 + 2)
#pragma unroll
        for (int j = 0; j < 8; ++j) STEP2(A0[j], A1[j])
        PREFETCH(A0, A1, c0 + 3)
#pragma unroll
        for (int j = 0; j < 8; ++j) STEP2(B0[j], B1[j])
        PREFETCH(B0, B1, c0 + 4)
#pragma unroll
        for (int j = 0; j < 8; ++j) STEP2(C0[j], C1[j])
        PREFETCH(C0, C1, c0 + 5)
#pragma unroll
        for (int j = 0; j < 8; ++j) STEP2(A0[j], A1[j])
        PREFETCH(A0, A1, c0 + 6)
#pragma unroll
        for (int j = 0; j < 8; ++j) STEP2(B0[j], B1[j])
        PREFETCH(B0, B1, c0 + 7)
#pragma unroll
        for (int j = 0; j < 8; ++j) STEP2(C0[j], C1[j])
    }
    // tail: A = rows 720..727, B[0]=728, B[1]=729
#pragma unroll
    for (int j = 0; j < 8; ++j) STEP2(A0[j], A1[j])
    STEP2(B0[0], B1[0])
    STEP2(B0[1], B1[1])
}

// ===========================================================================
// 8-lane butterfly reduction (groups of 8 consecutive lanes = one basin).
// ===========================================================================
template <int CTRL>
__device__ __forceinline__ float dpp_mov(float x) {
    int xi = __builtin_bit_cast(int, x);
    int r  = __builtin_amdgcn_update_dpp(0, xi, CTRL, 0xF, 0xF, true);
    return __builtin_bit_cast(float, r);
}
__device__ __forceinline__ float sum8(float v) {
    v += dpp_mov<0xB1>(v);    // xor 1
    v += dpp_mov<0x4E>(v);    // xor 2
    v += dpp_mov<0x141>(v);   // xor 4 within 8-group
    return v;
}

// ===========================================================================
// PASS B: t-parallel finalize on [t][SGW2] planes (R3-proven, stride bumped).
// Block = 256 thr = 32 basins x 8 members; grid (15, 32).
// 4-deep software-pipelined row loop over TT+14=64 rows; S[t-1] carried in
// a register (halo-seeded from sg[tbase-15]); 8-lane DPP reduce; qs/qg
// staged in LDS; 15-tap gamma-UH conv with b-across-lanes coalesced writes.
// ===========================================================================
__global__ __launch_bounds__(256) void finalize(const float* __restrict__ x,
                                                const float* __restrict__ raw,
                                                const float2* __restrict__ sg,
                                                float* __restrict__ out) {
    __shared__ float qsh[TT + 14][BBLK + 1];
    __shared__ float qgh[TT + 14][BBLK + 1];

    const int tid   = threadIdx.x;
    const int lb    = tid >> 3;          // local basin 0..31
    const int m     = tid & 7;
    const int tbase = blockIdx.x * TT;
    const int b0    = blockIdx.y * BBLK;
    const int b     = b0 + lb;
    const bool bval = b < NB;
    const int bc    = bval ? b : (NB - 1);      // clamped for loads
    const int lane  = bc * 8 + m;               // 0..7999

    const float* rp = raw + bc * 34;
    float pbm = rp[8 + m] * 450.0f + 50.0f;
    float e2s = 1.4426950408889634f / pbm;      // Y = Sn * exp2(pet * e2s)
    float omc = 1.0f - rp[16 + m];
    float dm  = rp[24 + m] * 0.89f + 0.01f;

    const float2* __restrict__ xf = (const float2*)x;

    // ---- 4-deep pipelined row loop: 64 rows ------------------------------
    float2 sgb[4], pvb[4];
#pragma unroll
    for (int d = 0; d < 4; ++d) {
        int tt = tbase + d - 14;
        int tc = tt < 0 ? 0 : (tt >= T_STEPS ? T_STEPS - 1 : tt);
        sgb[d] = sg[(size_t)tc * SGW2 + lane];
        pvb[d] = xf[tc * NB + bc];
    }
    float Sprev = (tbase > 0) ? sg[(size_t)(tbase - 15) * SGW2 + lane].x : 50.0f;

    for (int rr = 0; rr < TT + 14; rr += 4) {
#pragma unroll
        for (int d = 0; d < 4; ++d) {
            const int r  = rr + d;
            const int tt = tbase + r - 14;          // block-uniform
            float2 sgv = sgb[d];
            float2 pv  = pvb[d];
            {   // issue row r+4 load (clamped; tail loads harmless)
                int tn = tt + 4;
                int tc = tn < 0 ? 0 : (tn >= T_STEPS ? T_STEPS - 1 : tn);
                sgb[d] = sg[(size_t)tc * SGW2 + lane];
                pvb[d] = xf[tc * NB + bc];
            }
            const bool tval = (tt >= 0) && (tt < T_STEPS);
            float qs = 0.0f, qg = 0.0f, aet = 0.0f, sX = 0.0f, gX = 0.0f;
            if (tval) {
                float sp    = (tt == 0) ? 50.0f : Sprev;
                float y     = sgv.x * __builtin_amdgcn_exp2f(pv.y * e2s);
                float avail = (pv.x + sp) - y;
                qs  = omc * avail;
                qg  = dm * sgv.y;
                aet = y - sgv.x;
                sX  = sgv.x;
                gX  = sgv.y;
            }
            qs = sum8(qs);
            qg = sum8(qg);
            if (m == 0) { qsh[r][lb] = qs; qgh[r][lb] = qg; }
            if (r >= 14 && tval) {                   // own tile: ch3..5
                float a_s = sum8(aet);
                float s_s = sum8(sX);
                float g_s = sum8(gX);
                if (bval && m < 3) {
                    float v = (m == 0) ? a_s : ((m == 1) ? s_s : g_s);
                    out[((size_t)tt * NB + b) * 6 + 3 + m] = v * 0.125f;
                }
            }
            Sprev = sgv.x;
        }
    }
    __syncthreads();

    // ---- conv phase: threads = (t-slot 0..7) x (basin 0..31) -------------
    const int bl2 = tid & 31;
    const int tl0 = tid >> 5;                   // 0..7
    const int b2  = b0 + bl2;
    if (b2 >= NB) return;

    const float* rp2 = raw + b2 * 34;
    float ra = rp2[32] * 2.9f;
    float rb = rp2[33] * 6.5f;
    float aa = fmaxf(ra, 0.0f) + 0.1f;
    float th = fmaxf(rb, 0.0f) + 0.5f;
    float inv_th = 1.0f / th;
    float am1 = aa - 1.0f;
    float w[LENF];
    float sw = 0.0f;
#pragma unroll
    for (int k = 0; k < LENF; ++k) {
        float tk = (float)k + 0.5f;
        w[k] = __expf(am1 * __logf(tk) - tk * inv_th);
        sw += w[k];
    }
    float invs = 0.125f / sw;      // UH normalization x ensemble mean
#pragma unroll
    for (int k = 0; k < LENF; ++k) w[k] *= invs;

#pragma unroll
    for (int it = 0; it < 7; ++it) {
        int tl = tl0 + it * 8;                  // 0..55
        int t  = tbase + tl;
        if (tl < TT && t < T_STEPS) {
            float ys = 0.0f, yg = 0.0f;
#pragma unroll
            for (int k = 0; k < LENF; ++k) {
                ys = fmaf(qsh[tl + 14 - k][bl2], w[k], ys);
                yg = fmaf(qgh[tl + 14 - k][bl2], w[k], yg);
            }
            float* o = out + ((size_t)t * NB + b2) * 6;
            o[0] = ys + yg;
            o[1] = ys;
            o[2] = yg;
        }
    }
}

// ===========================================================================
// FALLBACK (ws too small for the 47MB state plane): R8's proven path.
// ===========================================================================
#define STEPF(CURV)                                                            \
  {                                                                            \
    float pcp = (CURV).x, pet = (CURV).y;                                      \
    float W     = pcp + S;                                                     \
    float term  = fmaf(W, inv2a, pb2a);                                        \
    float disc  = fmaf(term, term, -(W * boa));                                \
    float r     = __builtin_amdgcn_sqrtf(fmaxf(disc, NEARZ));                  \
    float Y     = term - r;                                                    \
    float e     = __builtin_amdgcn_exp2f(pet * ninvbl2);                       \
    float Sn    = Y * e;                                                       \
    float AET   = Y - Sn;                                                      \
    float avail = W - Y;                                                       \
    float Qs    = omc * avail;                                                 \
    float Gn    = fmaf(pc, avail, G) * inv1pd;                                 \
    float Qg    = pd * Gn;                                                     \
    S = Sn; G = Gn;                                                            \
    float qs_s = sum8(Qs);                                                     \
    float qg_s = sum8(Qg);                                                     \
    float ae_s = sum8(AET);                                                    \
    float s_s  = sum8(Sn);                                                     \
    float g_s  = sum8(Gn);                                                     \
    float v = qs_s;                                                            \
    v = (m == 1) ? qg_s : v;                                                   \
    v = (m == 2) ? ae_s : v;                                                   \
    v = (m == 3) ? s_s  : v;                                                   \
    v = (m >= 4) ? g_s  : v;                                                   \
    *optr = v * 0.125f;                                                        \
    optr += incr;                                                              \
  }

__global__ __launch_bounds__(64, 1) void scan_fb(const float* __restrict__ x,
                                                 const float* __restrict__ raw,
                                                 float* __restrict__ out,
                                                 float* __restrict__ qs_ws,
                                                 float* __restrict__ qg_ws,
                                                 float* __restrict__ dummy) {
    const int L  = threadIdx.x;
    const int lb = L >> 3;
    const int m  = L & 7;
    const int b  = blockIdx.x * 8 + lb;

    const float* rp = raw + b * 34;
    float pa = rp[0 * 8 + m] * 0.9f + 0.1f;
    float pb = rp[1 * 8 + m] * 450.0f + 50.0f;
    float pc = rp[2 * 8 + m];
    float pd = rp[3 * 8 + m] * 0.89f + 0.01f;
    float inv2a   = 1.0f / (2.0f * pa);
    float pb2a    = pb * inv2a;
    float boa     = pb / pa;
    float ninvbl2 = -1.4426950408889634f / pb;
    float omc     = 1.0f - pc;
    float inv1pd  = 1.0f / (1.0f + pd);

    float* optr;
    long long incr;
    if      (m == 0) { optr = qs_ws + b;                      incr = NB;     }
    else if (m == 1) { optr = qg_ws + b;                      incr = NB;     }
    else if (m <= 4) { optr = out + (long long)b * 6 + m + 1; incr = NB * 6; }
    else             { optr = dummy + (blockIdx.x * 64 + L);  incr = 0;      }

    float S = 50.0f, G = 10.0f;
    const float2* __restrict__ xf = (const float2*)x;

    float2 A[10], B[10], C[10];
#pragma unroll
    for (int j = 0; j < 10; ++j) A[j] = xf[j * NB + b];
#pragma unroll
    for (int j = 0; j < 10; ++j) B[j] = xf[(10 + j) * NB + b];

    for (int cg = 0; cg < 24; ++cg) {
        const int c0 = 3 * cg;
#pragma unroll
        for (int j = 0; j < 10; ++j) C[j] = xf[((c0 + 2) * 10 + j) * NB + b];
        __builtin_amdgcn_sched_barrier(0);
#pragma unroll
        for (int j = 0; j < 10; ++j) STEPF(A[j]);
#pragma unroll
        for (int j = 0; j < 10; ++j) A[j] = xf[((c0 + 3) * 10 + j) * NB + b];
        __builtin_amdgcn_sched_barrier(0);
#pragma unroll
        for (int j = 0; j < 10; ++j) STEPF(B[j]);
#pragma unroll
        for (int j = 0; j < 10; ++j) {
            int t = (c0 + 4) * 10 + j;
            t = t < T_STEPS ? t : (T_STEPS - 1);
            B[j] = xf[t * NB + b];
        }
        __builtin_amdgcn_sched_barrier(0);
#pragma unroll
        for (int j = 0; j < 10; ++j) STEPF(C[j]);
    }
#pragma unroll
    for (int j = 0; j < 10; ++j) STEPF(A[j]);
}

__global__ __launch_bounds__(256) void uh_fb(const float* __restrict__ raw,
                                             float* __restrict__ uh) {
    int b = blockIdx.x * 256 + threadIdx.x;
    if (b >= NB) return;
    float ra = raw[b * 34 + 32] * 2.9f;
    float rb = raw[b * 34 + 33] * 6.5f;
    float aa = fmaxf(ra, 0.0f) + 0.1f;
    float th = fmaxf(rb, 0.0f) + 0.5f;
    float inv_th = 1.0f / th;
    float am1 = aa - 1.0f;
    float w[LENF];
    float s = 0.0f;
#pragma unroll
    for (int k = 0; k < LENF; ++k) {
        float t = (float)k + 0.5f;
        w[k] = __expf(am1 * __logf(t) - t * inv_th);
        s += w[k];
    }
    float invs = 1.0f / s;
#pragma unroll
    for (int k = 0; k < LENF; ++k) uh[k * NB + b] = w[k] * invs;
}

__global__ __launch_bounds__(256) void conv_fb(const float* __restrict__ qs_ws,
                                               const float* __restrict__ qg_ws,
                                               const float* __restrict__ uh,
                                               float* __restrict__ out) {
    int b = blockIdx.x * 256 + threadIdx.x;
    int t = blockIdx.y;
    if (b >= NB) return;
    float ys = 0.0f, yg = 0.0f;
    int kmax = t < (LENF - 1) ? t : (LENF - 1);
    for (int k = 0; k <= kmax; ++k) {
        float w = uh[k * NB + b];
        ys = fmaf(qs_ws[(t - k) * NB + b], w, ys);
        yg = fmaf(qg_ws[(t - k) * NB + b], w, yg);
    }
    float* o = out + (t * NB + b) * 6;
    o[0] = ys + yg;
    o[1] = ys;
    o[2] = yg;
}

// ===========================================================================
extern "C" void kernel_launch(void* const* d_in, const int* in_sizes, int n_in,
                              void* d_out, int out_size, void* d_ws, size_t ws_size,
                              hipStream_t stream) {
    const float* x   = (const float*)d_in[0];   // (T,B,2) fp32
    const float* raw = (const float*)d_in[1];   // (B,34)  fp32
    float* out = (float*)d_out;                 // (T,B,6) fp32

    const size_t need = (size_t)T_STEPS * SGW2 * sizeof(float2);  // 47.1 MB
    if (ws_size >= need) {
        float2* sg = (float2*)d_ws;
        scan_state<<<dim3(63), dim3(64),  0, stream>>>(x, raw, sg);
        finalize  <<<dim3((T_STEPS + TT - 1) / TT, (NB + BBLK - 1) / BBLK),
                     dim3(256), 0, stream>>>(x, raw, sg, out);
    } else {
        float* qs = (float*)d_ws;
        float* qg = qs + (size_t)T_STEPS * NB;
        float* uh = qg + (size_t)T_STEPS * NB;
        float* dm = uh + (size_t)LENF * NB;
        uh_fb  <<<dim3((NB + 255) / 256),          dim3(256), 0, stream>>>(raw, uh);
        scan_fb<<<dim3(NB / 8),                    dim3(64),  0, stream>>>(x, raw, out, qs, qg, dm);
        conv_fb<<<dim3((NB + 255) / 256, T_STEPS), dim3(256), 0, stream>>>(qs, qg, uh, out);
    }
}

// Round 9
// 113.013 us; speedup vs baseline: 1.2509x; 1.2509x over previous
//
#include <hip/hip_runtime.h>
#include <math.h>

#define T_STEPS 730
#define NB      1000
#define LENF    15
#define NEARZ   1e-5f
#define SGW     8000           // plane width: 1000 basins x 8 members
#define NPAIR   365            // 730/2 (Sn,Gn) pairs per lane
#define TT      50             // finalize: t-rows per block (even!)
#define BBLK    32             // finalize: basins per block

// ===========================================================================
// R8 resubmit (R8 run died on container acquisition, not the kernel; code
// re-audited: rotation trace, pair indexing, Sprev seed all check out).
// R8 = R3 (best measured 113.6us) instruction-slimmed.  Session law (R1/R4/
// R6/R7): per-wave scan time ~ issued-slots x ~6.5cy; extra in-wave work
// does NOT hide under stalls (lone wave per SIMD, in-order, slow issue
// cadence).  So: cut slots, change nothing else.
//  1. exp2(pet*nbl) moved out of the step into a CONV stage one chunk ahead
//     (2 raw + 3 converted buffers, 6-phase rotation; ds_read->use distance
//     stays 8 steps -> no lgkm stalls).  Step loses 1 trans + 1 mul.
//  2. Paired float4 stores: plane [pair][lane] of (Sn0,Gn0,Sn1,Gn1); 365
//     stores+bumps instead of 730+730.  Bytes unchanged (bytes are not the
//     bound; slots are).
//  3. finalize loads the paired plane (half the state-load instructions).
// Step ledger: ~21 -> ~16.5 slots -> predict 131 -> ~105 cy/step.
// ===========================================================================

// ---- PASS A ---------------------------------------------------------------
// raw chunk load: 8 ds_read_b64 of (p,pet) for chunk CI (rows CI*8..CI*8+7)
#define DSLD(R, CI)                                                            \
  _Pragma("unroll")                                                            \
  for (int j = 0; j < 8; ++j) R[j] = xs[((CI) * 8 + j) * 8 + bl];              \
  __builtin_amdgcn_sched_barrier(0);

// convert raw (p,pet) -> (p, e=exp2(pet*nbl)); consumes a chunk read 1 phase
// ago (data long since arrived -> no wait)
#define CONV(V, R)                                                             \
  _Pragma("unroll")                                                            \
  for (int j = 0; j < 8; ++j)                                                  \
      V[j] = make_float2(R[j].x, __builtin_amdgcn_exp2f(R[j].y * nbl));

// two chained steps, one float4 store (.xy = even step, .zw = odd step)
#define STEPP(V0, V1)                                                          \
  {                                                                            \
    float W0  = (V0).x + S;                                                    \
    float t0  = fmaf(W0, inv2a, pb2a);                                         \
    float d0  = fmaf(t0, t0, -(W0 * boa));                                     \
    float r0  = __builtin_amdgcn_sqrtf(fmaxf(d0, NEARZ));                      \
    float Y0  = t0 - r0;                                                       \
    float Sn0 = Y0 * (V0).y;                                                   \
    float av0 = W0 - Y0;                                                       \
    float Gn0 = fmaf(pc, av0, G) * i1d;                                        \
    float W1  = (V1).x + Sn0;                                                  \
    float t1  = fmaf(W1, inv2a, pb2a);                                         \
    float d1  = fmaf(t1, t1, -(W1 * boa));                                     \
    float r1  = __builtin_amdgcn_sqrtf(fmaxf(d1, NEARZ));                      \
    float Y1  = t1 - r1;                                                       \
    float Sn1 = Y1 * (V1).y;                                                   \
    float av1 = W1 - Y1;                                                       \
    G = fmaf(pc, av1, Gn0) * i1d;                                              \
    S = Sn1;                                                                   \
    *ps4 = make_float4(Sn0, Gn0, Sn1, G);                                      \
    ps4 += SGW;                                                                \
  }

#define CONS(V) STEPP(V[0], V[1]) STEPP(V[2], V[3])                            \
                STEPP(V[4], V[5]) STEPP(V[6], V[7])

__global__ __launch_bounds__(64, 1) void scan_state(const float* __restrict__ x,
                                                    const float* __restrict__ raw,
                                                    float4* __restrict__ sg4) {
    __shared__ float4 xs4[2944];               // 736 rows x 8 basins x float2
    const float2* xs = (const float2*)xs4;

    const int L   = threadIdx.x;
    const int gid = blockIdx.x * 64 + L;       // 0..7999 (grid=125)
    const int b   = gid >> 3;
    const int m   = gid & 7;
    const int bl  = L >> 3;                    // basin-local 0..7

    // ---- one-time cooperative x -> LDS stage (R3-proven) ------------------
    {
        float4 tmp[46];
#pragma unroll
        for (int ch = 0; ch < 46; ++ch) {
            int idx = ch * 64 + L;             // 0..2943
            int row = idx >> 2;                // t row 0..735
            row = row < T_STEPS ? row : (T_STEPS - 1);
            tmp[ch] = *(const float4*)((const char*)x + (size_t)row * (NB * 8)
                                       + (size_t)(blockIdx.x * 64)
                                       + (size_t)(idx & 3) * 16);
        }
#pragma unroll
        for (int ch = 0; ch < 46; ++ch) xs4[ch * 64 + L] = tmp[ch];
    }
    __syncthreads();

    // raw layout (B,34) = [a(8), b(8), c(8), d(8), ra, rb]
    const float* rp = raw + b * 34;
    float pa = rp[0 * 8 + m] * 0.9f + 0.1f;
    float pb = rp[1 * 8 + m] * 450.0f + 50.0f;
    float pc = rp[2 * 8 + m];
    float pd = rp[3 * 8 + m] * 0.89f + 0.01f;

    float inv2a = 1.0f / (2.0f * pa);
    float pb2a  = pb * inv2a;
    float boa   = pb / pa;
    float nbl   = -1.4426950408889634f / pb;   // exp(-pet/b)=exp2(pet*this)
    float i1d   = 1.0f / (1.0f + pd);

    float S = 50.0f, G = 10.0f;
    float4* ps4 = sg4 + gid;                   // advances SGW float4 per pair

    // 6-phase rotation: phase c consumes chunk c.
    //   DSLD(R[c&1] <- c+2); CONV(V[(c+1)%3] <- R[(c+1)&1]); CONS(V[c%3])
    float2 Ra[8], Rb[8], V0[8], V1[8], V2[8];
    DSLD(Ra, 0)
    DSLD(Rb, 1)
    CONV(V0, Ra)

    for (int g = 0; g < 15; ++g) {             // chunks 6g .. 6g+5
        const int c0 = 6 * g;
        DSLD(Ra, c0 + 2)  CONV(V1, Rb)  CONS(V0)    // c = c0
        DSLD(Rb, c0 + 3)  CONV(V2, Ra)  CONS(V1)    // c+1
        DSLD(Ra, c0 + 4)  CONV(V0, Rb)  CONS(V2)    // c+2
        DSLD(Rb, c0 + 5)  CONV(V1, Ra)  CONS(V0)    // c+3
        DSLD(Ra, c0 + 6)  CONV(V2, Rb)  CONS(V1)    // c+4
        DSLD(Rb, c0 + 7)  CONV(V0, Ra)  CONS(V2)    // c+5
    }
    // after loop: consumed chunks 0..89; raw holds 90 (Ra), 91 (Rb);
    // V0 holds chunk 90 (converted at c=89).
    CONV(V1, Rb)   CONS(V0)                    // steps 720..727
    STEPP(V1[0], V1[1])                        // steps 728,729 (pair 364)
}

// ===========================================================================
// 8-lane butterfly reduction (groups of 8 consecutive lanes = one basin).
// ===========================================================================
template <int CTRL>
__device__ __forceinline__ float dpp_mov(float x) {
    int xi = __builtin_bit_cast(int, x);
    int r  = __builtin_amdgcn_update_dpp(0, xi, CTRL, 0xF, 0xF, true);
    return __builtin_bit_cast(float, r);
}
__device__ __forceinline__ float sum8(float v) {
    v += dpp_mov<0xB1>(v);    // xor 1
    v += dpp_mov<0x4E>(v);    // xor 2
    v += dpp_mov<0x141>(v);   // xor 4 within 8-group
    return v;
}

// ===========================================================================
// PASS B: t-parallel finalize on the PAIRED plane (R3 structure, half the
// state loads).  Block = 256 thr = 32 basins x 8 members; grid (15, 32).
// 4-deep pair pipeline over 32 pairs (64 rows incl 14 halo); S[t-1] carried
// in-register (seed = pair (tbase-16)/2 .z); 8-lane DPP reduce; qs/qg in
// LDS; 15-tap gamma-UH conv inline.
// ===========================================================================
#define ROW(SN, GN, XV, TTE, RE)                                               \
  {                                                                            \
    const int tt = (TTE); const int r = (RE);                                  \
    const bool tval = (tt >= 0) && (tt < T_STEPS);                             \
    float qs = 0.f, qg = 0.f, aet = 0.f, sX = 0.f, gX = 0.f;                   \
    if (tval) {                                                                \
      float sn  = (SN);                                                        \
      float spv = (tt == 0) ? 50.0f : Sprev;                                   \
      float y   = sn * __builtin_amdgcn_exp2f((XV).y * e2s);                   \
      float avail = ((XV).x + spv) - y;                                        \
      qs = omc * avail; qg = dm * (GN); aet = y - sn; sX = sn; gX = (GN);      \
      Sprev = sn;                                                              \
    }                                                                          \
    qs = sum8(qs); qg = sum8(qg);                                              \
    if (m == 0) { qsh[r][lb] = qs; qgh[r][lb] = qg; }                          \
    if (r >= 14 && tval) {                                                     \
      float a_s = sum8(aet), s_s = sum8(sX), g_s = sum8(gX);                   \
      if (bval && m < 3) {                                                     \
        float v = (m == 0) ? a_s : ((m == 1) ? s_s : g_s);                     \
        out[((size_t)tt * NB + b) * 6 + 3 + m] = v * 0.125f;                   \
      }                                                                        \
    }                                                                          \
  }

__global__ __launch_bounds__(256) void finalize(const float* __restrict__ x,
                                                const float* __restrict__ raw,
                                                const float4* __restrict__ sg4,
                                                float* __restrict__ out) {
    __shared__ float qsh[TT + 14][BBLK + 1];
    __shared__ float qgh[TT + 14][BBLK + 1];

    const int tid   = threadIdx.x;
    const int lb    = tid >> 3;          // local basin 0..31
    const int m     = tid & 7;
    const int tbase = blockIdx.x * TT;   // even
    const int b0    = blockIdx.y * BBLK;
    const int b     = b0 + lb;
    const bool bval = b < NB;
    const int bc    = bval ? b : (NB - 1);      // clamped for loads
    const int lane  = bc * 8 + m;               // 0..7999

    const float* rp = raw + bc * 34;
    float pbm = rp[8 + m] * 450.0f + 50.0f;
    float e2s = 1.4426950408889634f / pbm;      // y = sn * exp2(pet * e2s)
    float omc = 1.0f - rp[16 + m];
    float dm  = rp[24 + m] * 0.89f + 0.01f;

    const float2* __restrict__ xf = (const float2*)x;
    const int Pbase = (tbase - 14) >> 1;        // pair idx of row 0 (may be <0)

    // ---- 4-deep pair pipeline: 32 pairs = 64 rows ------------------------
    float4 sgb[4];
    float2 pv0[4], pv1[4];
#pragma unroll
    for (int d = 0; d < 4; ++d) {
        int P = Pbase + d; P = P < 0 ? 0 : (P > NPAIR - 1 ? NPAIR - 1 : P);
        sgb[d] = sg4[(size_t)P * SGW + lane];
        int t0 = tbase - 14 + 2 * d;
        int tc0 = t0 < 0 ? 0 : (t0 > T_STEPS - 1 ? T_STEPS - 1 : t0);
        int tc1 = t0 + 1 < 0 ? 0 : (t0 + 1 > T_STEPS - 1 ? T_STEPS - 1 : t0 + 1);
        pv0[d] = xf[tc0 * NB + bc];
        pv1[d] = xf[tc1 * NB + bc];
    }
    float Sprev = (tbase > 0)
        ? sg4[(size_t)((tbase - 16) >> 1) * SGW + lane].z   // Sn at t=tbase-15
        : 50.0f;

    for (int pp = 0; pp < 32; pp += 4) {
#pragma unroll
        for (int d = 0; d < 4; ++d) {
            const int p = pp + d;
            float4 sv = sgb[d];
            float2 x0 = pv0[d], x1 = pv1[d];
            {   // issue pair p+4 loads (clamped; tail loads harmless)
                int Pn = Pbase + p + 4;
                Pn = Pn < 0 ? 0 : (Pn > NPAIR - 1 ? NPAIR - 1 : Pn);
                sgb[d] = sg4[(size_t)Pn * SGW + lane];
                int tn = tbase - 14 + 2 * (p + 4);
                int tc0 = tn < 0 ? 0 : (tn > T_STEPS - 1 ? T_STEPS - 1 : tn);
                int tc1 = tn + 1 < 0 ? 0 : (tn + 1 > T_STEPS - 1 ? T_STEPS - 1 : tn + 1);
                pv0[d] = xf[tc0 * NB + bc];
                pv1[d] = xf[tc1 * NB + bc];
            }
            ROW(sv.x, sv.y, x0, tbase - 14 + 2 * p,     2 * p)
            ROW(sv.z, sv.w, x1, tbase - 14 + 2 * p + 1, 2 * p + 1)
        }
    }
    __syncthreads();

    // ---- conv phase: threads = (t-slot 0..7) x (basin 0..31) -------------
    const int bl2 = tid & 31;
    const int tl0 = tid >> 5;                   // 0..7
    const int b2  = b0 + bl2;
    if (b2 >= NB) return;

    const float* rp2 = raw + b2 * 34;
    float ra = rp2[32] * 2.9f;
    float rb = rp2[33] * 6.5f;
    float aa = fmaxf(ra, 0.0f) + 0.1f;
    float th = fmaxf(rb, 0.0f) + 0.5f;
    float inv_th = 1.0f / th;
    float am1 = aa - 1.0f;
    float w[LENF];
    float sw = 0.0f;
#pragma unroll
    for (int k = 0; k < LENF; ++k) {
        float tk = (float)k + 0.5f;
        w[k] = __expf(am1 * __logf(tk) - tk * inv_th);
        sw += w[k];
    }
    float invs = 0.125f / sw;      // UH normalization x ensemble mean
#pragma unroll
    for (int k = 0; k < LENF; ++k) w[k] *= invs;

#pragma unroll
    for (int it = 0; it < 7; ++it) {
        int tl = tl0 + it * 8;                  // 0..55
        int t  = tbase + tl;
        if (tl < TT && t < T_STEPS) {
            float ys = 0.0f, yg = 0.0f;
#pragma unroll
            for (int k = 0; k < LENF; ++k) {
                ys = fmaf(qsh[tl + 14 - k][bl2], w[k], ys);
                yg = fmaf(qgh[tl + 14 - k][bl2], w[k], yg);
            }
            float* o = out + ((size_t)t * NB + b2) * 6;
            o[0] = ys + yg;
            o[1] = ys;
            o[2] = yg;
        }
    }
}

// ===========================================================================
// FALLBACK (ws too small for the 47MB plane): R8's proven path.
// ===========================================================================
#define STEPF(CURV)                                                            \
  {                                                                            \
    float pcp = (CURV).x, pet = (CURV).y;                                      \
    float W     = pcp + S;                                                     \
    float term  = fmaf(W, inv2a, pb2a);                                        \
    float disc  = fmaf(term, term, -(W * boa));                                \
    float r     = __builtin_amdgcn_sqrtf(fmaxf(disc, NEARZ));                  \
    float Y     = term - r;                                                    \
    float e     = __builtin_amdgcn_exp2f(pet * ninvbl2);                       \
    float Sn    = Y * e;                                                       \
    float AET   = Y - Sn;                                                      \
    float avail = W - Y;                                                       \
    float Qs    = omc * avail;                                                 \
    float Gn    = fmaf(pc, avail, G) * inv1pd;                                 \
    float Qg    = pd * Gn;                                                     \
    S = Sn; G = Gn;                                                            \
    float qs_s = sum8(Qs);                                                     \
    float qg_s = sum8(Qg);                                                     \
    float ae_s = sum8(AET);                                                    \
    float s_s  = sum8(Sn);                                                     \
    float g_s  = sum8(Gn);                                                     \
    float v = qs_s;                                                            \
    v = (m == 1) ? qg_s : v;                                                   \
    v = (m == 2) ? ae_s : v;                                                   \
    v = (m == 3) ? s_s  : v;                                                   \
    v = (m >= 4) ? g_s  : v;                                                   \
    *optr = v * 0.125f;                                                        \
    optr += incr;                                                              \
  }

__global__ __launch_bounds__(64, 1) void scan_fb(const float* __restrict__ x,
                                                 const float* __restrict__ raw,
                                                 float* __restrict__ out,
                                                 float* __restrict__ qs_ws,
                                                 float* __restrict__ qg_ws,
                                                 float* __restrict__ dummy) {
    const int L  = threadIdx.x;
    const int lb = L >> 3;
    const int m  = L & 7;
    const int b  = blockIdx.x * 8 + lb;

    const float* rp = raw + b * 34;
    float pa = rp[0 * 8 + m] * 0.9f + 0.1f;
    float pb = rp[1 * 8 + m] * 450.0f + 50.0f;
    float pc = rp[2 * 8 + m];
    float pd = rp[3 * 8 + m] * 0.89f + 0.01f;
    float inv2a   = 1.0f / (2.0f * pa);
    float pb2a    = pb * inv2a;
    float boa     = pb / pa;
    float ninvbl2 = -1.4426950408889634f / pb;
    float omc     = 1.0f - pc;
    float inv1pd  = 1.0f / (1.0f + pd);

    float* optr;
    long long incr;
    if      (m == 0) { optr = qs_ws + b;                      incr = NB;     }
    else if (m == 1) { optr = qg_ws + b;                      incr = NB;     }
    else if (m <= 4) { optr = out + (long long)b * 6 + m + 1; incr = NB * 6; }
    else             { optr = dummy + (blockIdx.x * 64 + L);  incr = 0;      }

    float S = 50.0f, G = 10.0f;
    const float2* __restrict__ xf = (const float2*)x;

    float2 A[10], B[10], C[10];
#pragma unroll
    for (int j = 0; j < 10; ++j) A[j] = xf[j * NB + b];
#pragma unroll
    for (int j = 0; j < 10; ++j) B[j] = xf[(10 + j) * NB + b];

    for (int cg = 0; cg < 24; ++cg) {
        const int c0 = 3 * cg;
#pragma unroll
        for (int j = 0; j < 10; ++j) C[j] = xf[((c0 + 2) * 10 + j) * NB + b];
        __builtin_amdgcn_sched_barrier(0);
#pragma unroll
        for (int j = 0; j < 10; ++j) STEPF(A[j]);
#pragma unroll
        for (int j = 0; j < 10; ++j) A[j] = xf[((c0 + 3) * 10 + j) * NB + b];
        __builtin_amdgcn_sched_barrier(0);
#pragma unroll
        for (int j = 0; j < 10; ++j) STEPF(B[j]);
#pragma unroll
        for (int j = 0; j < 10; ++j) {
            int t = (c0 + 4) * 10 + j;
            t = t < T_STEPS ? t : (T_STEPS - 1);
            B[j] = xf[t * NB + b];
        }
        __builtin_amdgcn_sched_barrier(0);
#pragma unroll
        for (int j = 0; j < 10; ++j) STEPF(C[j]);
    }
#pragma unroll
    for (int j = 0; j < 10; ++j) STEPF(A[j]);
}

__global__ __launch_bounds__(256) void uh_fb(const float* __restrict__ raw,
                                             float* __restrict__ uh) {
    int b = blockIdx.x * 256 + threadIdx.x;
    if (b >= NB) return;
    float ra = raw[b * 34 + 32] * 2.9f;
    float rb = raw[b * 34 + 33] * 6.5f;
    float aa = fmaxf(ra, 0.0f) + 0.1f;
    float th = fmaxf(rb, 0.0f) + 0.5f;
    float inv_th = 1.0f / th;
    float am1 = aa - 1.0f;
    float w[LENF];
    float s = 0.0f;
#pragma unroll
    for (int k = 0; k < LENF; ++k) {
        float t = (float)k + 0.5f;
        w[k] = __expf(am1 * __logf(t) - t * inv_th);
        s += w[k];
    }
    float invs = 1.0f / s;
#pragma unroll
    for (int k = 0; k < LENF; ++k) uh[k * NB + b] = w[k] * invs;
}

__global__ __launch_bounds__(256) void conv_fb(const float* __restrict__ qs_ws,
                                               const float* __restrict__ qg_ws,
                                               const float* __restrict__ uh,
                                               float* __restrict__ out) {
    int b = blockIdx.x * 256 + threadIdx.x;
    int t = blockIdx.y;
    if (b >= NB) return;
    float ys = 0.0f, yg = 0.0f;
    int kmax = t < (LENF - 1) ? t : (LENF - 1);
    for (int k = 0; k <= kmax; ++k) {
        float w = uh[k * NB + b];
        ys = fmaf(qs_ws[(t - k) * NB + b], w, ys);
        yg = fmaf(qg_ws[(t - k) * NB + b], w, yg);
    }
    float* o = out + (t * NB + b) * 6;
    o[0] = ys + yg;
    o[1] = ys;
    o[2] = yg;
}

// ===========================================================================
extern "C" void kernel_launch(void* const* d_in, const int* in_sizes, int n_in,
                              void* d_out, int out_size, void* d_ws, size_t ws_size,
                              hipStream_t stream) {
    const float* x   = (const float*)d_in[0];   // (T,B,2) fp32
    const float* raw = (const float*)d_in[1];   // (B,34)  fp32
    float* out = (float*)d_out;                 // (T,B,6) fp32

    const size_t need = (size_t)NPAIR * SGW * sizeof(float4);  // 46.7 MB
    if (ws_size >= need) {
        float4* sg4 = (float4*)d_ws;
        scan_state<<<dim3(SGW / 64), dim3(64),  0, stream>>>(x, raw, sg4);
        finalize  <<<dim3((T_STEPS + TT - 1) / TT, (NB + BBLK - 1) / BBLK),
                     dim3(256), 0, stream>>>(x, raw, sg4, out);
    } else {
        float* qs = (float*)d_ws;
        float* qg = qs + (size_t)T_STEPS * NB;
        float* uh = qg + (size_t)T_STEPS * NB;
        float* dm = uh + (size_t)LENF * NB;
        uh_fb  <<<dim3((NB + 255) / 256),          dim3(256), 0, stream>>>(raw, uh);
        scan_fb<<<dim3(NB / 8),                    dim3(64),  0, stream>>>(x, raw, out, qs, qg, dm);
        conv_fb<<<dim3((NB + 255) / 256, T_STEPS), dim3(256), 0, stream>>>(qs, qg, uh, out);
    }
}